// Round 2
// baseline (2324.996 us; speedup 1.0000x reference)
//
#include <hip/hip_runtime.h>
#include <math.h>

#define B_ 8
#define CIN_ 128
#define COUT_ 256
#define N_ 8192
#define M_ 2048
#define K_ 16

// ---------------------------------------------------------------------------
// FPS v5: one block/batch, 256 thr x 32 pts (registers), 4 waves (1/SIMD).
// v4 per-iter was ~1770cy: 640cy frozen Phase A issue + ~1100cy serial reduce
// tail. v5 attacks the tail:
//   * combined u64 lex-max DPP reduce (key = kd<<32 | ~bi): ONE 6-step chain
//     (2 dpp + v_cmp_gt_u64 + 2 cndmask each) replaces umax chain + readlane
//     + cand + umin chain + readlane. Exact: max kd then min bi among ties;
//     shifted-in 0-key never wins (lo > 0 since bi <= 8191).
//   * lane 63 holds the reduced key -> writes kbuf directly (no readlanes).
//   * 4 waves: kbuf tree = 2x ds_read_b128 + 3 u64 selects (was 4+7, x8
//     waves); barrier skew + LDS pipe traffic halved.
// Decision math FROZEN (fmaf chain, strict >, ascending s, max-d / min-idx
// lex rule) — global winner = (max d, min original index) is invariant to
// the thread partition and reduce associativity, so the winner sequence is
// bit-identical to v4/v3/R11.
// ---------------------------------------------------------------------------
#define KSTEP(CTL) {                                                                     \
    unsigned h2 = (unsigned)__builtin_amdgcn_update_dpp(0, (int)hi, CTL, 0xf, 0xf, false); \
    unsigned l2 = (unsigned)__builtin_amdgcn_update_dpp(0, (int)lo, CTL, 0xf, 0xf, false); \
    unsigned long long cur = ((unsigned long long)hi << 32) | lo;                        \
    unsigned long long oth = ((unsigned long long)h2 << 32) | l2;                        \
    if (oth > cur) { hi = h2; lo = l2; } }

__global__ __launch_bounds__(256, 1) void fps_kernel(const float* __restrict__ coords,
                                                     float* __restrict__ fpts,
                                                     float* __restrict__ out_fps) {
#pragma clang fp contract(off)
    const int b = blockIdx.x;
    const int tid = threadIdx.x;
    const int lane = tid & 63;
    const int wid = tid >> 6;                    // 0..3
    const float* cb = coords + (size_t)b * 3 * N_;

    __shared__ float4 pts[N_];                   // 128 KiB
    __shared__ __align__(16) unsigned long long kbuf[2][4];
    __shared__ int wlist[M_];                    // 8 KiB winner indices

    float px[32], py[32], pz[32], mind[32];
#pragma unroll
    for (int s = 0; s < 32; ++s) {
        int p = tid + s * 256;
        px[s] = cb[p];
        py[s] = cb[N_ + p];
        pz[s] = cb[2 * N_ + p];
        mind[s] = 1e10f;
        pts[p] = make_float4(px[s], py[s], pz[s], 0.f);
    }
    __syncthreads();
    float4 p0 = pts[0];
    float lx = p0.x, ly = p0.y, lz = p0.z;

    int par = 0;
    for (int m = 1; m < M_; ++m) {
        float bv = -1.0f; int bs = 0;
#pragma unroll
        for (int s = 0; s < 32; ++s) {
            float dx = px[s] - lx;
            float dy = py[s] - ly;
            float dz = pz[s] - lz;
            float d = __builtin_fmaf(dz, dz, __builtin_fmaf(dy, dy, dx * dx));  // frozen
            float mn = fminf(mind[s], d);
            mind[s] = mn;
            if (mn > bv) { bv = mn; bs = s; }    // strict >, ascending s: min idx in thread
        }
        unsigned hi = __float_as_uint(bv);
        unsigned lo = 0xffffffffu - (unsigned)(tid + bs * 256);
        KSTEP(0x111)                              // row_shr:1
        KSTEP(0x112)                              // row_shr:2
        KSTEP(0x114)                              // row_shr:4
        KSTEP(0x118)                              // row_shr:8
        KSTEP(0x142)                              // row_bcast:15
        KSTEP(0x143)                              // row_bcast:31
        if (lane == 63)
            kbuf[par][wid] = ((unsigned long long)hi << 32) | (unsigned long long)lo;
        __syncthreads();
        // tree max over 4 wave keys (exact; keys distinct across waves)
        ulonglong2 q0 = *(const ulonglong2*)&kbuf[par][0];
        ulonglong2 q1 = *(const ulonglong2*)&kbuf[par][2];
        unsigned long long a0 = q0.x > q0.y ? q0.x : q0.y;
        unsigned long long a1 = q1.x > q1.y ? q1.x : q1.y;
        unsigned long long best = a0 > a1 ? a0 : a1;
        int widx = (int)(0xffffffffu - (unsigned)(best & 0xffffffffull));
        widx = ((unsigned)widx < (unsigned)N_) ? widx : 0;             // fault guard
        float4 wp = pts[widx];                                         // LDS broadcast
        lx = wp.x; ly = wp.y; lz = wp.z;
        if (tid == 0) wlist[m] = widx;
        par ^= 1;
    }

    // epilogue: 8 winners per thread, read wlist + pts after final barrier
    __syncthreads();
    for (int mm = tid; mm < M_; mm += 256) {
        int wi = (mm == 0) ? 0 : wlist[mm];
        wi = ((unsigned)wi < (unsigned)N_) ? wi : 0;                   // fault guard
        float4 wp = pts[wi];
        ((float4*)fpts)[b * M_ + mm] = make_float4(wp.x, wp.y, wp.z, 0.f);
        out_fps[(size_t)b * 3 * M_ + 0 * M_ + mm] = wp.x;
        out_fps[(size_t)b * 3 * M_ + 1 * M_ + mm] = wp.y;
        out_fps[(size_t)b * 3 * M_ + 2 * M_ + mm] = wp.z;
    }
}

// ---------------------------------------------------------------------------
// kNN: ONE WAVE per (b,m) row (R1 structure — empirically bit-equivalent to
// brute force via R1==R3 output equality). Top-16 as lane-distributed sorted
// list (lane r = rank r, lanes 16..63 sentinels); fast path = dist + 1 ballot
// per 64 candidates; inserts are wave-uniform shuffles. Distances use the
// FROZEN fmaf op order; sp staged once per block (per-point, row-independent).
// ---------------------------------------------------------------------------
__global__ __launch_bounds__(256) void knn_kernel(const float* __restrict__ coords,
                                                  const float* __restrict__ fpts,
                                                  int* __restrict__ knn) {
#pragma clang fp contract(off)
    const int bidx = blockIdx.x;
    const int b = bidx >> 9;                  // 512 blocks per batch
    const int mg = bidx & 511;
    const int tid = threadIdx.x;
    const int lane = tid & 63;
    const int w = tid >> 6;
    const int m = mg * 4 + w;
    const int row = b * M_ + m;
    const float* cb = coords + (size_t)b * 3 * N_;

    __shared__ float4 tile[1024];

    float4 f = ((const float4*)fpts)[row];
    const float fx = f.x, fy = f.y, fz = f.z;
    const float sf = __builtin_fmaf(fz, fz, __builtin_fmaf(fy, fy, fx * fx));  // frozen

    float ed = INFINITY; int ei = 0x7fffffff;     // distributed list entry
    float tau_d = INFINITY; int tau_i = 0x7fffffff;

    for (int t = 0; t < 8; ++t) {
        const int base = t * 1024;
#pragma unroll
        for (int j = 0; j < 4; ++j) {
            int idx = tid + 256 * j;
            int n = base + idx;
            float gx = cb[n], gy = cb[N_ + n], gz = cb[2 * N_ + n];
            float sp = __builtin_fmaf(gz, gz, __builtin_fmaf(gy, gy, gx * gx)); // frozen
            tile[idx] = make_float4(gx, gy, gz, sp);
        }
        __syncthreads();
        for (int s = 0; s < 16; ++s) {
            int l = s * 64 + lane;
            float4 p = tile[l];
            int n = base + l;
            float dot = __builtin_fmaf(fz, p.z, __builtin_fmaf(fy, p.y, fx * p.x)); // frozen
            float d = (sf + p.w) - 2.0f * dot;                                      // frozen
            bool q = (d < tau_d) || (d == tau_d && n < tau_i);
            unsigned long long bal = __ballot(q);
            while (bal) {
                int lb = __ffsll(bal) - 1;
                bal &= bal - 1;
                float dv = __shfl(d, lb);
                int   iv = __shfl(n, lb);
                if ((dv < tau_d) || (dv == tau_d && iv < tau_i)) {
                    float pud = __shfl_up(ed, 1);
                    int   pui = __shfl_up(ei, 1);
                    bool cs = (dv < ed) || (dv == ed && iv < ei);
                    bool cp = (lane != 0) && ((dv < pud) || (dv == pud && iv < pui));
                    ed = cs ? (cp ? pud : dv) : ed;
                    ei = cs ? (cp ? pui : iv) : ei;
                    tau_d = __shfl(ed, 15);
                    tau_i = __shfl(ei, 15);
                }
            }
        }
        __syncthreads();
    }
    if (lane < K_) {
        int v = ei;
        knn[(size_t)row * K_ + lane] = ((unsigned)v < (unsigned)N_) ? v : 0;  // fault guard
    }
}

// ---------------------------------------------------------------------------
// Per-point GEMM: hp[b][n][o] = sum_c x[b][c][n] * W[o][c]  (unchanged)
// ---------------------------------------------------------------------------
__global__ __launch_bounds__(256) void gemm_kernel(const float* __restrict__ x,
                                                   const float* __restrict__ W,
                                                   float* __restrict__ hp) {
    const int bid = blockIdx.x;
    const int b = bid >> 9;
    const int rem = bid & 511;
    const int n0 = (rem >> 2) * 64;
    const int o0 = (rem & 3) * 64;
    const int tid = threadIdx.x;
    const int tn = (tid & 15) * 4;
    const int to = (tid >> 4) * 4;
    const float* xg = x + (size_t)b * CIN_ * N_;

    __shared__ float Xs[64][64];
    __shared__ float Wt[64][68];

    float acc[4][4] = {};
    for (int kk = 0; kk < CIN_; kk += 64) {
#pragma unroll
        for (int i = 0; i < 16; ++i) {
            int e = tid + 256 * i;
            int r = e >> 6, q = e & 63;
            Xs[r][q] = xg[(size_t)(kk + r) * N_ + n0 + q];
            Wt[q][r] = W[(size_t)(o0 + r) * CIN_ + kk + q];
        }
        __syncthreads();
#pragma unroll 8
        for (int c = 0; c < 64; ++c) {
            float4 a = *(const float4*)&Xs[c][tn];
            float4 bb = *(const float4*)&Wt[c][to];
            float av[4] = {a.x, a.y, a.z, a.w};
            float bv[4] = {bb.x, bb.y, bb.z, bb.w};
#pragma unroll
            for (int j = 0; j < 4; ++j)
#pragma unroll
                for (int l = 0; l < 4; ++l)
                    acc[j][l] += av[j] * bv[l];
        }
        __syncthreads();
    }
#pragma unroll
    for (int j = 0; j < 4; ++j) {
        float4 v = make_float4(acc[j][0], acc[j][1], acc[j][2], acc[j][3]);
        *(float4*)&hp[((size_t)b * N_ + n0 + tn + j) * COUT_ + o0 + to] = v;
    }
}

// ---------------------------------------------------------------------------
// BN stats stage 1: deterministic per-block f64 partials (unchanged).
// ---------------------------------------------------------------------------
__global__ __launch_bounds__(256) void stats_partial_kernel(const float* __restrict__ hp,
                                                            const int* __restrict__ knn,
                                                            double* __restrict__ partial,
                                                            double* __restrict__ partial2) {
    const int o = threadIdx.x;
    const int g0 = blockIdx.x * 1024;              // 262144 gathered rows total
    double s = 0.0, s2 = 0.0;
    for (int r = 0; r < 1024; ++r) {
        int g = g0 + r;                            // g = (b*M + m)*K + k
        int row = g >> 4;
        int k = g & 15;
        int b = row >> 11;
        int n = knn[row * K_ + k];
        n = ((unsigned)n < (unsigned)N_) ? n : 0;  // fault guard
        double h = (double)hp[((size_t)b * N_ + n) * COUT_ + o];
        s += h;
        s2 += h * h;
    }
    partial[(size_t)blockIdx.x * 256 + o] = s;
    partial2[(size_t)blockIdx.x * 256 + o] = s2;
}

__global__ void bn_final_kernel(const double* __restrict__ partial,
                                const double* __restrict__ partial2,
                                const float* __restrict__ gamma,
                                const float* __restrict__ beta,
                                float* __restrict__ scale,
                                float* __restrict__ bias) {
    int o = threadIdx.x;
    double s = 0.0, s2 = 0.0;
    for (int j = 0; j < 256; ++j) {
        s += partial[(size_t)j * 256 + o];
        s2 += partial2[(size_t)j * 256 + o];
    }
    const double inv = 1.0 / (double)(B_ * M_ * K_);
    double mean = s * inv;
    double var = s2 * inv - mean * mean;
    if (var < 0.0) var = 0.0;
    double r = 1.0 / sqrt(var + 1e-5);
    double g = (double)gamma[o];
    scale[o] = (float)(r * g);
    bias[o] = (float)((double)beta[o] - mean * r * g);
}

// ---------------------------------------------------------------------------
// Finalize: y[b][o][m] = relu( max_k ( hp[gather] * scale + bias ) ) (unchanged)
// ---------------------------------------------------------------------------
__global__ __launch_bounds__(256) void finalize_kernel(const float* __restrict__ hp,
                                                       const int* __restrict__ knn,
                                                       const float* __restrict__ scale,
                                                       const float* __restrict__ bias,
                                                       float* __restrict__ y) {
    const int b = blockIdx.x >> 6;
    const int m0 = (blockIdx.x & 63) * 32;
    const int tid = threadIdx.x;
    __shared__ int kidx[512];
    __shared__ float tile[32][257];

    for (int e = tid; e < 512; e += 256) {
        int n = knn[(b * M_ + m0 + (e >> 4)) * K_ + (e & 15)];
        kidx[e] = ((unsigned)n < (unsigned)N_) ? n : 0;   // fault guard
    }
    __syncthreads();

    const float s = scale[tid];
    const float t = bias[tid];
    const float* hb = hp + (size_t)b * N_ * COUT_;
    for (int mm = 0; mm < 32; ++mm) {
        float v = -INFINITY;
#pragma unroll
        for (int k = 0; k < K_; ++k) {
            int n = kidx[mm * 16 + k];
            float h = hb[(size_t)n * COUT_ + tid];
            v = fmaxf(v, h * s + t);
        }
        v = fmaxf(v, 0.0f);
        tile[mm][tid] = v;
    }
    __syncthreads();
#pragma unroll
    for (int r = 0; r < 32; ++r) {
        int o2 = r * 8 + (tid >> 5);
        int mm = tid & 31;
        y[((size_t)b * COUT_ + o2) * M_ + m0 + mm] = tile[mm][o2];
    }
}

__global__ void sentinel_kernel(float* out, float v) { out[0] = v; }

// ---------------------------------------------------------------------------
extern "C" void kernel_launch(void* const* d_in, const int* in_sizes, int n_in,
                              void* d_out, int out_size, void* d_ws, size_t ws_size,
                              hipStream_t stream) {
    const float* x = (const float*)d_in[0];
    const float* coords = (const float*)d_in[1];
    const float* W = (const float*)d_in[2];
    const float* gamma = (const float*)d_in[3];
    const float* beta = (const float*)d_in[4];
    float* y = (float*)d_out;
    float* out_fps = y + (size_t)B_ * COUT_ * M_;     // fps_coords after y (f32)

    if (n_in != 5 ||
        in_sizes[0] != B_ * CIN_ * N_ ||
        in_sizes[1] != B_ * 3 * N_ ||
        in_sizes[2] != COUT_ * CIN_ ||
        in_sizes[3] != COUT_ || in_sizes[4] != COUT_ ||
        out_size != B_ * COUT_ * M_ + B_ * 3 * M_) {
        sentinel_kernel<<<1, 1, 0, stream>>>(y, -2.0e6f);
        return;
    }

    const size_t HP_BYTES = (size_t)B_ * N_ * COUT_ * 4;          // 64 MB
    const size_t FPTS_BYTES = (size_t)B_ * M_ * 16;               // 256 KB
    const size_t KNN_BYTES = (size_t)B_ * M_ * K_ * 4;            // 1 MB
    const size_t PART_BYTES = (size_t)256 * 256 * 8;              // 512 KB
    const size_t NEED = HP_BYTES + FPTS_BYTES + KNN_BYTES + 2 * PART_BYTES + 8192;
    if (ws_size < NEED) {
        sentinel_kernel<<<1, 1, 0, stream>>>(y, -1.0e6f);
        return;
    }
    char* ws = (char*)d_ws;
    float* hp = (float*)ws;
    float* fpts = (float*)(ws + HP_BYTES);
    int* knn = (int*)(ws + HP_BYTES + FPTS_BYTES);
    double* partial = (double*)(ws + HP_BYTES + FPTS_BYTES + KNN_BYTES);
    double* partial2 = (double*)(ws + HP_BYTES + FPTS_BYTES + KNN_BYTES + PART_BYTES);
    float* scale = (float*)(ws + HP_BYTES + FPTS_BYTES + KNN_BYTES + 2 * PART_BYTES);
    float* bias = scale + 256;

    fps_kernel<<<B_, 256, 0, stream>>>(coords, fpts, out_fps);
    knn_kernel<<<B_ * 512, 256, 0, stream>>>(coords, fpts, knn);
    gemm_kernel<<<B_ * 512, 256, 0, stream>>>(x, W, hp);
    stats_partial_kernel<<<256, 256, 0, stream>>>(hp, knn, partial, partial2);
    bn_final_kernel<<<1, 256, 0, stream>>>(partial, partial2, gamma, beta, scale, bias);
    finalize_kernel<<<512, 256, 0, stream>>>(hp, knn, scale, bias, y);
}

// Round 3
// 2008.109 us; speedup vs baseline: 1.1578x; 1.1578x over previous
//
#include <hip/hip_runtime.h>
#include <math.h>

#define B_ 8
#define CIN_ 128
#define COUT_ 256
#define N_ 8192
#define M_ 2048
#define K_ 16

// ---------------------------------------------------------------------------
// FPS v6: one block/batch, 512 thr x 16 pts (R1 partition — measured best:
// 2 waves/SIMD, VALUBusy 98% of the 8-CU bound = pure issue-bound; R2 proved
// 1 wave/SIMD exposes latency, -23%). Instruction cuts grafted from R2's
// bit-verified pieces:
//   * combined u64 lex-max DPP chain (key = d_bits<<32 | ~idx), ONE 6-step
//     chain, no readlanes (R2-verified exact).
//   * lane 63 (holds reduced key after row_bcast:31) publishes via LDS
//     atomicMax(u64) = ds_max_u64 to a single slot — replaces per-wave
//     4x ds_read_b128 + 7-deep u64 tree scan. Lex-max over packed keys is
//     exact; slot init 0 never wins (lo > 0 always). Parity double-buffer;
//     tid0 clears slot[par^1] right after the barrier — next atomic to that
//     slot is >=320cy away (Phase A of next iter must issue first).
//   * wlist LDS winner log + epilogue writeout (R2-verified) instead of
//     per-iter w0/w1 bookkeeping.
// Decision math FROZEN (fmaf chain, strict >, ascending s, max-d / min-idx
// lex rule) — winner sequence bit-identical.
// ---------------------------------------------------------------------------
#define KSTEP(CTL) {                                                                     \
    unsigned h2 = (unsigned)__builtin_amdgcn_update_dpp(0, (int)hi, CTL, 0xf, 0xf, false); \
    unsigned l2 = (unsigned)__builtin_amdgcn_update_dpp(0, (int)lo, CTL, 0xf, 0xf, false); \
    unsigned long long cur = ((unsigned long long)hi << 32) | lo;                        \
    unsigned long long oth = ((unsigned long long)h2 << 32) | l2;                        \
    if (oth > cur) { hi = h2; lo = l2; } }

__global__ __launch_bounds__(512) void fps_kernel(const float* __restrict__ coords,
                                                  float* __restrict__ fpts,
                                                  float* __restrict__ out_fps) {
#pragma clang fp contract(off)
    const int b = blockIdx.x;
    const int tid = threadIdx.x;
    const int lane = tid & 63;
    const float* cb = coords + (size_t)b * 3 * N_;

    __shared__ float4 pts[N_];                   // 128 KiB
    __shared__ unsigned long long slot[2];
    __shared__ int wlist[M_];                    // 8 KiB winner indices

    float px[16], py[16], pz[16], mind[16];
#pragma unroll
    for (int s = 0; s < 16; ++s) {
        int p = tid + s * 512;
        px[s] = cb[p];
        py[s] = cb[N_ + p];
        pz[s] = cb[2 * N_ + p];
        mind[s] = 1e10f;
        pts[p] = make_float4(px[s], py[s], pz[s], 0.f);
    }
    if (tid == 0) { slot[0] = 0ull; slot[1] = 0ull; }
    __syncthreads();
    float4 p0 = pts[0];
    float lx = p0.x, ly = p0.y, lz = p0.z;

    int par = 0;
    for (int m = 1; m < M_; ++m) {
        float bv = -1.0f; int bs = 0;
#pragma unroll
        for (int s = 0; s < 16; ++s) {
            float dx = px[s] - lx;
            float dy = py[s] - ly;
            float dz = pz[s] - lz;
            float d = __builtin_fmaf(dz, dz, __builtin_fmaf(dy, dy, dx * dx));  // frozen
            float mn = fminf(mind[s], d);
            mind[s] = mn;
            if (mn > bv) { bv = mn; bs = s; }    // strict >, ascending s: min idx in thread
        }
        unsigned hi = __float_as_uint(bv);
        unsigned lo = 0xffffffffu - (unsigned)(tid + bs * 512);
        KSTEP(0x111)                              // row_shr:1
        KSTEP(0x112)                              // row_shr:2
        KSTEP(0x114)                              // row_shr:4
        KSTEP(0x118)                              // row_shr:8
        KSTEP(0x142)                              // row_bcast:15
        KSTEP(0x143)                              // row_bcast:31
        if (lane == 63)
            atomicMax(&slot[par], ((unsigned long long)hi << 32) | (unsigned long long)lo);
        __syncthreads();
        if (tid == 0) slot[par ^ 1] = 0ull;       // clear other slot; next atomic to it
                                                  // is >=320cy away (next Phase A first)
        unsigned long long best = slot[par];
        int widx = (int)(0xffffffffu - (unsigned)(best & 0xffffffffull));
        widx = ((unsigned)widx < (unsigned)N_) ? widx : 0;             // fault guard
        float4 wp = pts[widx];                                         // LDS broadcast
        lx = wp.x; ly = wp.y; lz = wp.z;
        if (tid == 0) wlist[m] = widx;
        par ^= 1;
    }

    // epilogue: 4 winners per thread, read wlist + pts after final barrier
    __syncthreads();
    for (int mm = tid; mm < M_; mm += 512) {
        int wi = (mm == 0) ? 0 : wlist[mm];
        wi = ((unsigned)wi < (unsigned)N_) ? wi : 0;                   // fault guard
        float4 wp = pts[wi];
        ((float4*)fpts)[b * M_ + mm] = make_float4(wp.x, wp.y, wp.z, 0.f);
        out_fps[(size_t)b * 3 * M_ + 0 * M_ + mm] = wp.x;
        out_fps[(size_t)b * 3 * M_ + 1 * M_ + mm] = wp.y;
        out_fps[(size_t)b * 3 * M_ + 2 * M_ + mm] = wp.z;
    }
}

// ---------------------------------------------------------------------------
// kNN: ONE WAVE per (b,m) row (R1 structure — empirically bit-equivalent to
// brute force via R1==R3 output equality). Top-16 as lane-distributed sorted
// list (lane r = rank r, lanes 16..63 sentinels); fast path = dist + 1 ballot
// per 64 candidates; inserts are wave-uniform shuffles. Distances use the
// FROZEN fmaf op order; sp staged once per block (per-point, row-independent).
// ---------------------------------------------------------------------------
__global__ __launch_bounds__(256) void knn_kernel(const float* __restrict__ coords,
                                                  const float* __restrict__ fpts,
                                                  int* __restrict__ knn) {
#pragma clang fp contract(off)
    const int bidx = blockIdx.x;
    const int b = bidx >> 9;                  // 512 blocks per batch
    const int mg = bidx & 511;
    const int tid = threadIdx.x;
    const int lane = tid & 63;
    const int w = tid >> 6;
    const int m = mg * 4 + w;
    const int row = b * M_ + m;
    const float* cb = coords + (size_t)b * 3 * N_;

    __shared__ float4 tile[1024];

    float4 f = ((const float4*)fpts)[row];
    const float fx = f.x, fy = f.y, fz = f.z;
    const float sf = __builtin_fmaf(fz, fz, __builtin_fmaf(fy, fy, fx * fx));  // frozen

    float ed = INFINITY; int ei = 0x7fffffff;     // distributed list entry
    float tau_d = INFINITY; int tau_i = 0x7fffffff;

    for (int t = 0; t < 8; ++t) {
        const int base = t * 1024;
#pragma unroll
        for (int j = 0; j < 4; ++j) {
            int idx = tid + 256 * j;
            int n = base + idx;
            float gx = cb[n], gy = cb[N_ + n], gz = cb[2 * N_ + n];
            float sp = __builtin_fmaf(gz, gz, __builtin_fmaf(gy, gy, gx * gx)); // frozen
            tile[idx] = make_float4(gx, gy, gz, sp);
        }
        __syncthreads();
        for (int s = 0; s < 16; ++s) {
            int l = s * 64 + lane;
            float4 p = tile[l];
            int n = base + l;
            float dot = __builtin_fmaf(fz, p.z, __builtin_fmaf(fy, p.y, fx * p.x)); // frozen
            float d = (sf + p.w) - 2.0f * dot;                                      // frozen
            bool q = (d < tau_d) || (d == tau_d && n < tau_i);
            unsigned long long bal = __ballot(q);
            while (bal) {
                int lb = __ffsll(bal) - 1;
                bal &= bal - 1;
                float dv = __shfl(d, lb);
                int   iv = __shfl(n, lb);
                if ((dv < tau_d) || (dv == tau_d && iv < tau_i)) {
                    float pud = __shfl_up(ed, 1);
                    int   pui = __shfl_up(ei, 1);
                    bool cs = (dv < ed) || (dv == ed && iv < ei);
                    bool cp = (lane != 0) && ((dv < pud) || (dv == pud && iv < pui));
                    ed = cs ? (cp ? pud : dv) : ed;
                    ei = cs ? (cp ? pui : iv) : ei;
                    tau_d = __shfl(ed, 15);
                    tau_i = __shfl(ei, 15);
                }
            }
        }
        __syncthreads();
    }
    if (lane < K_) {
        int v = ei;
        knn[(size_t)row * K_ + lane] = ((unsigned)v < (unsigned)N_) ? v : 0;  // fault guard
    }
}

// ---------------------------------------------------------------------------
// Per-point GEMM: hp[b][n][o] = sum_c x[b][c][n] * W[o][c]  (unchanged)
// ---------------------------------------------------------------------------
__global__ __launch_bounds__(256) void gemm_kernel(const float* __restrict__ x,
                                                   const float* __restrict__ W,
                                                   float* __restrict__ hp) {
    const int bid = blockIdx.x;
    const int b = bid >> 9;
    const int rem = bid & 511;
    const int n0 = (rem >> 2) * 64;
    const int o0 = (rem & 3) * 64;
    const int tid = threadIdx.x;
    const int tn = (tid & 15) * 4;
    const int to = (tid >> 4) * 4;
    const float* xg = x + (size_t)b * CIN_ * N_;

    __shared__ float Xs[64][64];
    __shared__ float Wt[64][68];

    float acc[4][4] = {};
    for (int kk = 0; kk < CIN_; kk += 64) {
#pragma unroll
        for (int i = 0; i < 16; ++i) {
            int e = tid + 256 * i;
            int r = e >> 6, q = e & 63;
            Xs[r][q] = xg[(size_t)(kk + r) * N_ + n0 + q];
            Wt[q][r] = W[(size_t)(o0 + r) * CIN_ + kk + q];
        }
        __syncthreads();
#pragma unroll 8
        for (int c = 0; c < 64; ++c) {
            float4 a = *(const float4*)&Xs[c][tn];
            float4 bb = *(const float4*)&Wt[c][to];
            float av[4] = {a.x, a.y, a.z, a.w};
            float bv[4] = {bb.x, bb.y, bb.z, bb.w};
#pragma unroll
            for (int j = 0; j < 4; ++j)
#pragma unroll
                for (int l = 0; l < 4; ++l)
                    acc[j][l] += av[j] * bv[l];
        }
        __syncthreads();
    }
#pragma unroll
    for (int j = 0; j < 4; ++j) {
        float4 v = make_float4(acc[j][0], acc[j][1], acc[j][2], acc[j][3]);
        *(float4*)&hp[((size_t)b * N_ + n0 + tn + j) * COUT_ + o0 + to] = v;
    }
}

// ---------------------------------------------------------------------------
// BN stats stage 1: deterministic per-block f64 partials (unchanged).
// ---------------------------------------------------------------------------
__global__ __launch_bounds__(256) void stats_partial_kernel(const float* __restrict__ hp,
                                                            const int* __restrict__ knn,
                                                            double* __restrict__ partial,
                                                            double* __restrict__ partial2) {
    const int o = threadIdx.x;
    const int g0 = blockIdx.x * 1024;              // 262144 gathered rows total
    double s = 0.0, s2 = 0.0;
    for (int r = 0; r < 1024; ++r) {
        int g = g0 + r;                            // g = (b*M + m)*K + k
        int row = g >> 4;
        int k = g & 15;
        int b = row >> 11;
        int n = knn[row * K_ + k];
        n = ((unsigned)n < (unsigned)N_) ? n : 0;  // fault guard
        double h = (double)hp[((size_t)b * N_ + n) * COUT_ + o];
        s += h;
        s2 += h * h;
    }
    partial[(size_t)blockIdx.x * 256 + o] = s;
    partial2[(size_t)blockIdx.x * 256 + o] = s2;
}

__global__ void bn_final_kernel(const double* __restrict__ partial,
                                const double* __restrict__ partial2,
                                const float* __restrict__ gamma,
                                const float* __restrict__ beta,
                                float* __restrict__ scale,
                                float* __restrict__ bias) {
    int o = threadIdx.x;
    double s = 0.0, s2 = 0.0;
    for (int j = 0; j < 256; ++j) {
        s += partial[(size_t)j * 256 + o];
        s2 += partial2[(size_t)j * 256 + o];
    }
    const double inv = 1.0 / (double)(B_ * M_ * K_);
    double mean = s * inv;
    double var = s2 * inv - mean * mean;
    if (var < 0.0) var = 0.0;
    double r = 1.0 / sqrt(var + 1e-5);
    double g = (double)gamma[o];
    scale[o] = (float)(r * g);
    bias[o] = (float)((double)beta[o] - mean * r * g);
}

// ---------------------------------------------------------------------------
// Finalize: y[b][o][m] = relu( max_k ( hp[gather] * scale + bias ) ) (unchanged)
// ---------------------------------------------------------------------------
__global__ __launch_bounds__(256) void finalize_kernel(const float* __restrict__ hp,
                                                       const int* __restrict__ knn,
                                                       const float* __restrict__ scale,
                                                       const float* __restrict__ bias,
                                                       float* __restrict__ y) {
    const int b = blockIdx.x >> 6;
    const int m0 = (blockIdx.x & 63) * 32;
    const int tid = threadIdx.x;
    __shared__ int kidx[512];
    __shared__ float tile[32][257];

    for (int e = tid; e < 512; e += 256) {
        int n = knn[(b * M_ + m0 + (e >> 4)) * K_ + (e & 15)];
        kidx[e] = ((unsigned)n < (unsigned)N_) ? n : 0;   // fault guard
    }
    __syncthreads();

    const float s = scale[tid];
    const float t = bias[tid];
    const float* hb = hp + (size_t)b * N_ * COUT_;
    for (int mm = 0; mm < 32; ++mm) {
        float v = -INFINITY;
#pragma unroll
        for (int k = 0; k < K_; ++k) {
            int n = kidx[mm * 16 + k];
            float h = hb[(size_t)n * COUT_ + tid];
            v = fmaxf(v, h * s + t);
        }
        v = fmaxf(v, 0.0f);
        tile[mm][tid] = v;
    }
    __syncthreads();
#pragma unroll
    for (int r = 0; r < 32; ++r) {
        int o2 = r * 8 + (tid >> 5);
        int mm = tid & 31;
        y[((size_t)b * COUT_ + o2) * M_ + m0 + mm] = tile[mm][o2];
    }
}

__global__ void sentinel_kernel(float* out, float v) { out[0] = v; }

// ---------------------------------------------------------------------------
extern "C" void kernel_launch(void* const* d_in, const int* in_sizes, int n_in,
                              void* d_out, int out_size, void* d_ws, size_t ws_size,
                              hipStream_t stream) {
    const float* x = (const float*)d_in[0];
    const float* coords = (const float*)d_in[1];
    const float* W = (const float*)d_in[2];
    const float* gamma = (const float*)d_in[3];
    const float* beta = (const float*)d_in[4];
    float* y = (float*)d_out;
    float* out_fps = y + (size_t)B_ * COUT_ * M_;     // fps_coords after y (f32)

    if (n_in != 5 ||
        in_sizes[0] != B_ * CIN_ * N_ ||
        in_sizes[1] != B_ * 3 * N_ ||
        in_sizes[2] != COUT_ * CIN_ ||
        in_sizes[3] != COUT_ || in_sizes[4] != COUT_ ||
        out_size != B_ * COUT_ * M_ + B_ * 3 * M_) {
        sentinel_kernel<<<1, 1, 0, stream>>>(y, -2.0e6f);
        return;
    }

    const size_t HP_BYTES = (size_t)B_ * N_ * COUT_ * 4;          // 64 MB
    const size_t FPTS_BYTES = (size_t)B_ * M_ * 16;               // 256 KB
    const size_t KNN_BYTES = (size_t)B_ * M_ * K_ * 4;            // 1 MB
    const size_t PART_BYTES = (size_t)256 * 256 * 8;              // 512 KB
    const size_t NEED = HP_BYTES + FPTS_BYTES + KNN_BYTES + 2 * PART_BYTES + 8192;
    if (ws_size < NEED) {
        sentinel_kernel<<<1, 1, 0, stream>>>(y, -1.0e6f);
        return;
    }
    char* ws = (char*)d_ws;
    float* hp = (float*)ws;
    float* fpts = (float*)(ws + HP_BYTES);
    int* knn = (int*)(ws + HP_BYTES + FPTS_BYTES);
    double* partial = (double*)(ws + HP_BYTES + FPTS_BYTES + KNN_BYTES);
    double* partial2 = (double*)(ws + HP_BYTES + FPTS_BYTES + KNN_BYTES + PART_BYTES);
    float* scale = (float*)(ws + HP_BYTES + FPTS_BYTES + KNN_BYTES + 2 * PART_BYTES);
    float* bias = scale + 256;

    fps_kernel<<<B_, 512, 0, stream>>>(coords, fpts, out_fps);
    knn_kernel<<<B_ * 512, 256, 0, stream>>>(coords, fpts, knn);
    gemm_kernel<<<B_ * 512, 256, 0, stream>>>(x, W, hp);
    stats_partial_kernel<<<256, 256, 0, stream>>>(hp, knn, partial, partial2);
    bn_final_kernel<<<1, 256, 0, stream>>>(partial, partial2, gamma, beta, scale, bias);
    finalize_kernel<<<512, 256, 0, stream>>>(hp, knn, scale, bias, y);
}

// Round 4
// 1896.194 us; speedup vs baseline: 1.2261x; 1.0590x over previous
//
#include <hip/hip_runtime.h>
#include <math.h>

#define B_ 8
#define CIN_ 128
#define COUT_ 256
#define N_ 8192
#define M_ 2048
#define K_ 16

#define GEMM_BLOCKS 2048   // 8 b * (8192/128 n-tiles) * (256/64 o-tiles)

// ---------------------------------------------------------------------------
// DPP wave reductions (row_shr 1/2/4/8 + row_bcast 15/31): VALU-latency only.
// (R1/v4 exact form — measured best fps: 1510us, VALUBusy at the 8-CU issue
// bound. R3's combined-u64 chain + ds_max_u64 was 30 instr vs 26 and slower.)
// ---------------------------------------------------------------------------
__device__ __forceinline__ unsigned umax2(unsigned a, unsigned b) { return a > b ? a : b; }
__device__ __forceinline__ unsigned umin2(unsigned a, unsigned b) { return a < b ? a : b; }

__device__ __forceinline__ unsigned wave_reduce_umax(unsigned v) {
    v = umax2(v, (unsigned)__builtin_amdgcn_update_dpp(0, (int)v, 0x111, 0xf, 0xf, false));
    v = umax2(v, (unsigned)__builtin_amdgcn_update_dpp(0, (int)v, 0x112, 0xf, 0xf, false));
    v = umax2(v, (unsigned)__builtin_amdgcn_update_dpp(0, (int)v, 0x114, 0xf, 0xf, false));
    v = umax2(v, (unsigned)__builtin_amdgcn_update_dpp(0, (int)v, 0x118, 0xf, 0xf, false));
    v = umax2(v, (unsigned)__builtin_amdgcn_update_dpp(0, (int)v, 0x142, 0xf, 0xf, false));
    v = umax2(v, (unsigned)__builtin_amdgcn_update_dpp(0, (int)v, 0x143, 0xf, 0xf, false));
    return (unsigned)__builtin_amdgcn_readlane((int)v, 63);
}
__device__ __forceinline__ unsigned wave_reduce_umin(unsigned v) {
    v = umin2(v, (unsigned)__builtin_amdgcn_update_dpp(-1, (int)v, 0x111, 0xf, 0xf, false));
    v = umin2(v, (unsigned)__builtin_amdgcn_update_dpp(-1, (int)v, 0x112, 0xf, 0xf, false));
    v = umin2(v, (unsigned)__builtin_amdgcn_update_dpp(-1, (int)v, 0x114, 0xf, 0xf, false));
    v = umin2(v, (unsigned)__builtin_amdgcn_update_dpp(-1, (int)v, 0x118, 0xf, 0xf, false));
    v = umin2(v, (unsigned)__builtin_amdgcn_update_dpp(-1, (int)v, 0x142, 0xf, 0xf, false));
    v = umin2(v, (unsigned)__builtin_amdgcn_update_dpp(-1, (int)v, 0x143, 0xf, 0xf, false));
    return (unsigned)__builtin_amdgcn_readlane((int)v, 63);
}

// ---------------------------------------------------------------------------
// MEGA kernel: blocks 0..7 = FPS (R1/v4 verbatim), blocks 8..8+2047 = GEMM.
// FPS occupies 8 CUs for ~1.5ms; GEMM (no dependency on FPS) fills the other
// 248 CUs concurrently. LDS union = max(139.4KB fps, 49KB gemm): a GEMM
// block can never co-reside with an FPS block (139.4+49 > 160KB), so FPS CUs
// stay dedicated. GEMM retiled 128x64 for 512 thr with per-element
// accumulation order preserved (c asc within kk, kk asc) -> hp bit-identical
// to the old 64x64/256thr kernel. FPS decision math FROZEN.
// ---------------------------------------------------------------------------
__global__ __launch_bounds__(512) void fps_gemm_kernel(const float* __restrict__ coords,
                                                       const float* __restrict__ x,
                                                       const float* __restrict__ W,
                                                       float* __restrict__ fpts,
                                                       float* __restrict__ out_fps,
                                                       float* __restrict__ hp) {
    __shared__ union {
        struct {
            float4 pts[N_];                      // 128 KiB
            unsigned long long kbuf[2][8];
            int wlist[M_];                       // 8 KiB
        } f;
        struct {
            float Xs[64][128];                   // 32 KiB
            float Wt[64][68];                    // 17 KiB
        } g;
    } sm;

    const int tid = threadIdx.x;

    if (blockIdx.x < B_) {
        // ================= FPS (R1/v4 exact) =================
#pragma clang fp contract(off)
        const int b = blockIdx.x;
        const int lane = tid & 63;
        const int wid = tid >> 6;                // 0..7
        const float* cb = coords + (size_t)b * 3 * N_;
        float4* pts = sm.f.pts;
        unsigned long long (*kbuf)[8] = sm.f.kbuf;
        int* wlist = sm.f.wlist;

        float px[16], py[16], pz[16], mind[16];
#pragma unroll
        for (int s = 0; s < 16; ++s) {
            int p = tid + s * 512;
            px[s] = cb[p];
            py[s] = cb[N_ + p];
            pz[s] = cb[2 * N_ + p];
            mind[s] = 1e10f;
            pts[p] = make_float4(px[s], py[s], pz[s], 0.f);
        }
        __syncthreads();
        float4 p0 = pts[0];
        float lx = p0.x, ly = p0.y, lz = p0.z;

        int par = 0;
        for (int m = 1; m < M_; ++m) {
            float bv = -1.0f; int bs = 0;
#pragma unroll
            for (int s = 0; s < 16; ++s) {
                float dx = px[s] - lx;
                float dy = py[s] - ly;
                float dz = pz[s] - lz;
                float d = __builtin_fmaf(dz, dz, __builtin_fmaf(dy, dy, dx * dx));  // frozen
                float mn = fminf(mind[s], d);
                mind[s] = mn;
                if (mn > bv) { bv = mn; bs = s; }   // strict >, ascending s: min idx in thread
            }
            int bi = tid + bs * 512;
            unsigned kd = __float_as_uint(bv);
            unsigned md = wave_reduce_umax(kd);
            unsigned cand = (kd == md) ? (unsigned)bi : 0xffffffffu;
            unsigned mi = wave_reduce_umin(cand);
            if (lane == 0)
                kbuf[par][wid] = ((unsigned long long)md << 32) |
                                 (unsigned long long)(0xffffffffu - mi);   // u64 max == lex rule
            __syncthreads();
            // vectorized tree max over 8 wave keys (exact; keys distinct across waves)
            const unsigned long long* kb = kbuf[par];
            ulonglong2 q0 = *(const ulonglong2*)&kb[0];
            ulonglong2 q1 = *(const ulonglong2*)&kb[2];
            ulonglong2 q2 = *(const ulonglong2*)&kb[4];
            ulonglong2 q3 = *(const ulonglong2*)&kb[6];
            unsigned long long a0 = q0.x > q0.y ? q0.x : q0.y;
            unsigned long long a1 = q1.x > q1.y ? q1.x : q1.y;
            unsigned long long a2 = q2.x > q2.y ? q2.x : q2.y;
            unsigned long long a3 = q3.x > q3.y ? q3.x : q3.y;
            unsigned long long b01 = a0 > a1 ? a0 : a1;
            unsigned long long b23 = a2 > a3 ? a2 : a3;
            unsigned long long best = b01 > b23 ? b01 : b23;
            int widx = (int)(0xffffffffu - (unsigned)(best & 0xffffffffull));
            widx = ((unsigned)widx < (unsigned)N_) ? widx : 0;             // fault guard
            float4 wp = pts[widx];                                         // LDS broadcast
            lx = wp.x; ly = wp.y; lz = wp.z;
            if (tid == 0) wlist[m] = widx;
            par ^= 1;
        }

        // epilogue: 4 winners per thread, read wlist + pts after final barrier
        __syncthreads();
        for (int mm = tid; mm < M_; mm += 512) {
            int wi = (mm == 0) ? 0 : wlist[mm];
            wi = ((unsigned)wi < (unsigned)N_) ? wi : 0;                   // fault guard
            float4 wp = pts[wi];
            ((float4*)fpts)[b * M_ + mm] = make_float4(wp.x, wp.y, wp.z, 0.f);
            out_fps[(size_t)b * 3 * M_ + 0 * M_ + mm] = wp.x;
            out_fps[(size_t)b * 3 * M_ + 1 * M_ + mm] = wp.y;
            out_fps[(size_t)b * 3 * M_ + 2 * M_ + mm] = wp.z;
        }
    } else {
        // ================= GEMM: hp[b][n][o] = sum_c x[b][c][n] * W[o][c] ===
        // 128(n) x 64(o) tile, 512 thr, acc[4][4]; accumulation order per
        // output element identical to previous kernel (c asc within kk, kk asc).
        const int gb = blockIdx.x - B_;
        const int b = gb >> 8;                    // 256 tiles per batch
        const int rem = gb & 255;
        const int n0 = (rem >> 2) * 128;
        const int o0 = (rem & 3) * 64;
        const int tn = (tid & 31) * 4;            // 0..124
        const int to = (tid >> 5) * 4;            // 0..60
        const float* xg = x + (size_t)b * CIN_ * N_;
        float (*Xs)[128] = sm.g.Xs;
        float (*Wt)[68] = sm.g.Wt;

        float acc[4][4] = {};
        for (int kk = 0; kk < CIN_; kk += 64) {
#pragma unroll
            for (int i = 0; i < 16; ++i) {        // 8192 elems of Xs
                int e = tid + 512 * i;
                int r = e >> 7, q = e & 127;
                Xs[r][q] = xg[(size_t)(kk + r) * N_ + n0 + q];
            }
#pragma unroll
            for (int i = 0; i < 8; ++i) {         // 4096 elems of Wt
                int e = tid + 512 * i;
                int r = e >> 6, q = e & 63;
                Wt[q][r] = W[(size_t)(o0 + r) * CIN_ + kk + q];
            }
            __syncthreads();
#pragma unroll 8
            for (int c = 0; c < 64; ++c) {
                float4 a = *(const float4*)&Xs[c][tn];
                float4 bb = *(const float4*)&Wt[c][to];
                float av[4] = {a.x, a.y, a.z, a.w};
                float bv[4] = {bb.x, bb.y, bb.z, bb.w};
#pragma unroll
                for (int j = 0; j < 4; ++j)
#pragma unroll
                    for (int l = 0; l < 4; ++l)
                        acc[j][l] += av[j] * bv[l];
            }
            __syncthreads();
        }
#pragma unroll
        for (int j = 0; j < 4; ++j) {
            float4 v = make_float4(acc[j][0], acc[j][1], acc[j][2], acc[j][3]);
            *(float4*)&hp[((size_t)b * N_ + n0 + tn + j) * COUT_ + o0 + to] = v;
        }
    }
}

// ---------------------------------------------------------------------------
// kNN: ONE WAVE per (b,m) row (R1 structure — empirically bit-equivalent to
// brute force via R1==R3 output equality). Top-16 as lane-distributed sorted
// list (lane r = rank r, lanes 16..63 sentinels); fast path = dist + 1 ballot
// per 64 candidates; inserts are wave-uniform shuffles. Distances use the
// FROZEN fmaf op order; sp staged once per block (per-point, row-independent).
// ---------------------------------------------------------------------------
__global__ __launch_bounds__(256) void knn_kernel(const float* __restrict__ coords,
                                                  const float* __restrict__ fpts,
                                                  int* __restrict__ knn) {
#pragma clang fp contract(off)
    const int bidx = blockIdx.x;
    const int b = bidx >> 9;                  // 512 blocks per batch
    const int mg = bidx & 511;
    const int tid = threadIdx.x;
    const int lane = tid & 63;
    const int w = tid >> 6;
    const int m = mg * 4 + w;
    const int row = b * M_ + m;
    const float* cb = coords + (size_t)b * 3 * N_;

    __shared__ float4 tile[1024];

    float4 f = ((const float4*)fpts)[row];
    const float fx = f.x, fy = f.y, fz = f.z;
    const float sf = __builtin_fmaf(fz, fz, __builtin_fmaf(fy, fy, fx * fx));  // frozen

    float ed = INFINITY; int ei = 0x7fffffff;     // distributed list entry
    float tau_d = INFINITY; int tau_i = 0x7fffffff;

    for (int t = 0; t < 8; ++t) {
        const int base = t * 1024;
#pragma unroll
        for (int j = 0; j < 4; ++j) {
            int idx = tid + 256 * j;
            int n = base + idx;
            float gx = cb[n], gy = cb[N_ + n], gz = cb[2 * N_ + n];
            float sp = __builtin_fmaf(gz, gz, __builtin_fmaf(gy, gy, gx * gx)); // frozen
            tile[idx] = make_float4(gx, gy, gz, sp);
        }
        __syncthreads();
        for (int s = 0; s < 16; ++s) {
            int l = s * 64 + lane;
            float4 p = tile[l];
            int n = base + l;
            float dot = __builtin_fmaf(fz, p.z, __builtin_fmaf(fy, p.y, fx * p.x)); // frozen
            float d = (sf + p.w) - 2.0f * dot;                                      // frozen
            bool q = (d < tau_d) || (d == tau_d && n < tau_i);
            unsigned long long bal = __ballot(q);
            while (bal) {
                int lb = __ffsll(bal) - 1;
                bal &= bal - 1;
                float dv = __shfl(d, lb);
                int   iv = __shfl(n, lb);
                if ((dv < tau_d) || (dv == tau_d && iv < tau_i)) {
                    float pud = __shfl_up(ed, 1);
                    int   pui = __shfl_up(ei, 1);
                    bool cs = (dv < ed) || (dv == ed && iv < ei);
                    bool cp = (lane != 0) && ((dv < pud) || (dv == pud && iv < pui));
                    ed = cs ? (cp ? pud : dv) : ed;
                    ei = cs ? (cp ? pui : iv) : ei;
                    tau_d = __shfl(ed, 15);
                    tau_i = __shfl(ei, 15);
                }
            }
        }
        __syncthreads();
    }
    if (lane < K_) {
        int v = ei;
        knn[(size_t)row * K_ + lane] = ((unsigned)v < (unsigned)N_) ? v : 0;  // fault guard
    }
}

// ---------------------------------------------------------------------------
// BN stats stage 1: deterministic per-block f64 partials (unchanged).
// ---------------------------------------------------------------------------
__global__ __launch_bounds__(256) void stats_partial_kernel(const float* __restrict__ hp,
                                                            const int* __restrict__ knn,
                                                            double* __restrict__ partial,
                                                            double* __restrict__ partial2) {
    const int o = threadIdx.x;
    const int g0 = blockIdx.x * 1024;              // 262144 gathered rows total
    double s = 0.0, s2 = 0.0;
    for (int r = 0; r < 1024; ++r) {
        int g = g0 + r;                            // g = (b*M + m)*K + k
        int row = g >> 4;
        int k = g & 15;
        int b = row >> 11;
        int n = knn[row * K_ + k];
        n = ((unsigned)n < (unsigned)N_) ? n : 0;  // fault guard
        double h = (double)hp[((size_t)b * N_ + n) * COUT_ + o];
        s += h;
        s2 += h * h;
    }
    partial[(size_t)blockIdx.x * 256 + o] = s;
    partial2[(size_t)blockIdx.x * 256 + o] = s2;
}

__global__ void bn_final_kernel(const double* __restrict__ partial,
                                const double* __restrict__ partial2,
                                const float* __restrict__ gamma,
                                const float* __restrict__ beta,
                                float* __restrict__ scale,
                                float* __restrict__ bias) {
    int o = threadIdx.x;
    double s = 0.0, s2 = 0.0;
    for (int j = 0; j < 256; ++j) {
        s += partial[(size_t)j * 256 + o];
        s2 += partial2[(size_t)j * 256 + o];
    }
    const double inv = 1.0 / (double)(B_ * M_ * K_);
    double mean = s * inv;
    double var = s2 * inv - mean * mean;
    if (var < 0.0) var = 0.0;
    double r = 1.0 / sqrt(var + 1e-5);
    double g = (double)gamma[o];
    scale[o] = (float)(r * g);
    bias[o] = (float)((double)beta[o] - mean * r * g);
}

// ---------------------------------------------------------------------------
// Finalize: y[b][o][m] = relu( max_k ( hp[gather] * scale + bias ) ) (unchanged)
// ---------------------------------------------------------------------------
__global__ __launch_bounds__(256) void finalize_kernel(const float* __restrict__ hp,
                                                       const int* __restrict__ knn,
                                                       const float* __restrict__ scale,
                                                       const float* __restrict__ bias,
                                                       float* __restrict__ y) {
    const int b = blockIdx.x >> 6;
    const int m0 = (blockIdx.x & 63) * 32;
    const int tid = threadIdx.x;
    __shared__ int kidx[512];
    __shared__ float tile[32][257];

    for (int e = tid; e < 512; e += 256) {
        int n = knn[(b * M_ + m0 + (e >> 4)) * K_ + (e & 15)];
        kidx[e] = ((unsigned)n < (unsigned)N_) ? n : 0;   // fault guard
    }
    __syncthreads();

    const float s = scale[tid];
    const float t = bias[tid];
    const float* hb = hp + (size_t)b * N_ * COUT_;
    for (int mm = 0; mm < 32; ++mm) {
        float v = -INFINITY;
#pragma unroll
        for (int k = 0; k < K_; ++k) {
            int n = kidx[mm * 16 + k];
            float h = hb[(size_t)n * COUT_ + tid];
            v = fmaxf(v, h * s + t);
        }
        v = fmaxf(v, 0.0f);
        tile[mm][tid] = v;
    }
    __syncthreads();
#pragma unroll
    for (int r = 0; r < 32; ++r) {
        int o2 = r * 8 + (tid >> 5);
        int mm = tid & 31;
        y[((size_t)b * COUT_ + o2) * M_ + m0 + mm] = tile[mm][o2];
    }
}

__global__ void sentinel_kernel(float* out, float v) { out[0] = v; }

// ---------------------------------------------------------------------------
extern "C" void kernel_launch(void* const* d_in, const int* in_sizes, int n_in,
                              void* d_out, int out_size, void* d_ws, size_t ws_size,
                              hipStream_t stream) {
    const float* x = (const float*)d_in[0];
    const float* coords = (const float*)d_in[1];
    const float* W = (const float*)d_in[2];
    const float* gamma = (const float*)d_in[3];
    const float* beta = (const float*)d_in[4];
    float* y = (float*)d_out;
    float* out_fps = y + (size_t)B_ * COUT_ * M_;     // fps_coords after y (f32)

    if (n_in != 5 ||
        in_sizes[0] != B_ * CIN_ * N_ ||
        in_sizes[1] != B_ * 3 * N_ ||
        in_sizes[2] != COUT_ * CIN_ ||
        in_sizes[3] != COUT_ || in_sizes[4] != COUT_ ||
        out_size != B_ * COUT_ * M_ + B_ * 3 * M_) {
        sentinel_kernel<<<1, 1, 0, stream>>>(y, -2.0e6f);
        return;
    }

    const size_t HP_BYTES = (size_t)B_ * N_ * COUT_ * 4;          // 64 MB
    const size_t FPTS_BYTES = (size_t)B_ * M_ * 16;               // 256 KB
    const size_t KNN_BYTES = (size_t)B_ * M_ * K_ * 4;            // 1 MB
    const size_t PART_BYTES = (size_t)256 * 256 * 8;              // 512 KB
    const size_t NEED = HP_BYTES + FPTS_BYTES + KNN_BYTES + 2 * PART_BYTES + 8192;
    if (ws_size < NEED) {
        sentinel_kernel<<<1, 1, 0, stream>>>(y, -1.0e6f);
        return;
    }
    char* ws = (char*)d_ws;
    float* hp = (float*)ws;
    float* fpts = (float*)(ws + HP_BYTES);
    int* knn = (int*)(ws + HP_BYTES + FPTS_BYTES);
    double* partial = (double*)(ws + HP_BYTES + FPTS_BYTES + KNN_BYTES);
    double* partial2 = (double*)(ws + HP_BYTES + FPTS_BYTES + KNN_BYTES + PART_BYTES);
    float* scale = (float*)(ws + HP_BYTES + FPTS_BYTES + KNN_BYTES + 2 * PART_BYTES);
    float* bias = scale + 256;

    fps_gemm_kernel<<<B_ + GEMM_BLOCKS, 512, 0, stream>>>(coords, x, W, fpts, out_fps, hp);
    knn_kernel<<<B_ * 512, 256, 0, stream>>>(coords, fpts, knn);
    stats_partial_kernel<<<256, 256, 0, stream>>>(hp, knn, partial, partial2);
    bn_final_kernel<<<1, 256, 0, stream>>>(partial, partial2, gamma, beta, scale, bias);
    finalize_kernel<<<512, 256, 0, stream>>>(hp, knn, scale, bias, y);
}